// Round 8
// baseline (435.131 us; speedup 1.0000x reference)
//
#include <hip/hip_runtime.h>
#include <hip/hip_bf16.h>
#include <cstdint>
#include <cstddef>

#define NN 8192
#define FIN 128
#define FOUT 64

typedef __attribute__((ext_vector_type(8))) short short8;
typedef __attribute__((ext_vector_type(4))) float f32x4;

__device__ __forceinline__ unsigned short f32_to_bf16_bits(float f) {
    union { float f; uint32_t u; } c; c.f = f;
    uint32_t u = c.u;
    u += 0x7fffu + ((u >> 16) & 1u);   // RNE
    return (unsigned short)(u >> 16);
}

// Kernel 1: Wh = x @ W^T (bf16, stored transposed [f][i]); Wh1 = Wh@a1; Wh2 = Wh@a2
__global__ __launch_bounds__(256) void gat_prep(
    const float* __restrict__ x, const float* __restrict__ W,
    const float* __restrict__ a, unsigned short* __restrict__ WhT,
    float* __restrict__ Wh1, float* __restrict__ Wh2)
{
    const int t    = threadIdx.x;
    const int f    = t & 63;        // lane = feature
    const int iloc = t >> 6;        // wave = local row
    const int i    = blockIdx.x * 4 + iloc;

    const float4* x4 = (const float4*)(x + (size_t)i * FIN);  // wave-uniform
    const float4* w4 = (const float4*)(W + (size_t)f * FIN);

    float acc = 0.f;
#pragma unroll
    for (int k = 0; k < FIN / 4; ++k) {
        float4 xv = x4[k];
        float4 wv = w4[k];
        acc += xv.x * wv.x + xv.y * wv.y + xv.z * wv.z + xv.w * wv.w;
    }

    WhT[(size_t)f * NN + i] = f32_to_bf16_bits(acc);

    float r1 = acc * a[f];
    float r2 = acc * a[64 + f];
#pragma unroll
    for (int m = 1; m < 64; m <<= 1) {
        r1 += __shfl_xor(r1, m, 64);
        r2 += __shfl_xor(r2, m, 64);
    }
    if (f == 0) { Wh1[i] = r1; Wh2[i] = r2; }
}

// Kernel 2 (fused): 512 blocks x 512 threads (8 waves). Each block owns a
// 16-row panel and the FULL j range (8192). Wave w covers j-strip
// [w*32 + tt*256, +32) for tt=0..31.
//
// Round-8 discriminating schedule (all pressure-safe, ~106 VGPR, no spill):
//   - adj : 3-deep prefetch (HBM stream ~900cy; issue-to-use ~3 iterations
//           ~600+cy — tests the latency theory).
//   - Wh2 : 1-deep (32 KB, L1/L2-resident broadcast).
//   - B   : JIT-early (issued at top of body, ~150cy of CALC before MFMA
//           use covers most of L2 latency; frees 16 VGPR vs staging).
// Outcome decodes theory: ~410us = adj latency; ~430us = L1-BW bound
// (bytes unchanged); ~450us = B-JIT toxic (must stage B).
__global__ __launch_bounds__(512, 4) void gat_attn(
    const int* __restrict__ adj, const unsigned short* __restrict__ WhT,
    const float* __restrict__ Wh1, const float* __restrict__ Wh2,
    float* __restrict__ out)
{
    __shared__ float lds_C[8][16][68];   // +4 pad: 2-way (free) bank aliasing
    __shared__ float lds_tot[8][16];

    const int tid  = threadIdx.x;
    const int wave = tid >> 6;       // 0..7
    const int lane = tid & 63;
    const int il   = lane & 15;      // A-fragment row (i)
    const int q    = lane >> 4;      // quad -> k offset q*8
    const int i0   = blockIdx.x * 16;
    const int i    = i0 + il;

    const float wh1   = Wh1[i];
    const int   jbase = wave * 32 + q * 8;
    const int* __restrict__ adjrow = adj + (size_t)i * NN;

    const short8* bp0 = (const short8*)(WhT + (size_t)(0  + il) * NN);
    const short8* bp1 = (const short8*)(WhT + (size_t)(16 + il) * NN);
    const short8* bp2 = (const short8*)(WhT + (size_t)(32 + il) * NN);
    const short8* bp3 = (const short8*)(WhT + (size_t)(48 + il) * NN);

    f32x4 acc0 = {0.f, 0.f, 0.f, 0.f};
    f32x4 acc1 = {0.f, 0.f, 0.f, 0.f};
    f32x4 acc2 = {0.f, 0.f, 0.f, 0.f};
    f32x4 acc3 = {0.f, 0.f, 0.f, 0.f};
    float tot0 = 0.f, tot1 = 0.f;

    // ---- pipeline prologue ----
    // adj 3-deep: iters 0,1,2
    int4   aA0 = *(const int4*)(adjrow + jbase);
    int4   aA1 = *(const int4*)(adjrow + jbase + 4);
    int4   aB0 = *(const int4*)(adjrow + jbase + 256);
    int4   aB1 = *(const int4*)(adjrow + jbase + 260);
    int4   aC0 = *(const int4*)(adjrow + jbase + 512);
    int4   aC1 = *(const int4*)(adjrow + jbase + 516);
    // Wh2 1-deep: iter 0
    float4 wA0 = *(const float4*)(Wh2 + jbase);
    float4 wA1 = *(const float4*)(Wh2 + jbase + 4);

#pragma unroll 1
    for (int tt = 0; tt < 32; ++tt) {
        // ---- prefetch adj for iter tt+3 (wraps; dead loads on tail) ----
        const int jn3 = jbase + (((tt + 3) & 31) << 8);
        const int4 nav0 = *(const int4*)(adjrow + jn3);
        const int4 nav1 = *(const int4*)(adjrow + jn3 + 4);

        // ---- prefetch Wh2 for iter tt+1 ----
        const int jn1 = jbase + (((tt + 1) & 31) << 8);
        const float4 nw20 = *(const float4*)(Wh2 + jn1);
        const float4 nw21 = *(const float4*)(Wh2 + jn1 + 4);

        // ---- B fragments for THIS iteration, JIT-early: issued here,
        //      consumed after ~150cy of CALC/cvt below ----
        const int jb = (jbase + (tt << 8)) >> 3;
        const short8 b0 = bp0[jb];
        const short8 b1 = bp1[jb];
        const short8 b2 = bp2[jb];
        const short8 b3 = bp3[jb];

        // ---- compute iter tt ----
        float wv[8];
#define CALC(idx, adjv, wh2v, totv)                                    \
        {                                                              \
            float s = wh1 + (wh2v);                                    \
            float e = fmaxf(s, 0.2f * s);      /* leaky_relu 0.2 */    \
            float v = ((adjv) > 0) ? __expf(e) : 0.f;                  \
            totv += v;                                                 \
            wv[idx] = v;                                               \
        }
        CALC(0, aA0.x, wA0.x, tot0) CALC(1, aA0.y, wA0.y, tot1)
        CALC(2, aA0.z, wA0.z, tot0) CALC(3, aA0.w, wA0.w, tot1)
        CALC(4, aA1.x, wA1.x, tot0) CALC(5, aA1.y, wA1.y, tot1)
        CALC(6, aA1.z, wA1.z, tot0) CALC(7, aA1.w, wA1.w, tot1)
#undef CALC

        // packed RNE f32->bf16 (v_cvt_pk_bf16_f32 on gfx950)
        union { short8 v; __hip_bfloat162 h[4]; } af;
        af.h[0] = __float22bfloat162_rn(float2{wv[0], wv[1]});
        af.h[1] = __float22bfloat162_rn(float2{wv[2], wv[3]});
        af.h[2] = __float22bfloat162_rn(float2{wv[4], wv[5]});
        af.h[3] = __float22bfloat162_rn(float2{wv[6], wv[7]});

        acc0 = __builtin_amdgcn_mfma_f32_16x16x32_bf16(af.v, b0, acc0, 0, 0, 0);
        acc1 = __builtin_amdgcn_mfma_f32_16x16x32_bf16(af.v, b1, acc1, 0, 0, 0);
        acc2 = __builtin_amdgcn_mfma_f32_16x16x32_bf16(af.v, b2, acc2, 0, 0, 0);
        acc3 = __builtin_amdgcn_mfma_f32_16x16x32_bf16(af.v, b3, acc3, 0, 0, 0);

        // ---- rotate pipeline registers ----
        aA0 = aB0; aA1 = aB1;          // adj: 3-deep shift
        aB0 = aC0; aB1 = aC1;
        aC0 = nav0; aC1 = nav1;
        wA0 = nw20; wA1 = nw21;        // Wh2: 1-deep
    }

    // row-total reduction: lanes {il, il+16, il+32, il+48} hold partials
    float tot = tot0 + tot1;
    tot += __shfl_xor(tot, 16, 64);
    tot += __shfl_xor(tot, 32, 64);
    if (lane < 16) lds_tot[wave][lane] = tot;

    // C/D layout: col = lane&15 (f within tile), row = q*4 + reg (i)
#pragma unroll
    for (int r = 0; r < 4; ++r) {
        lds_C[wave][q * 4 + r][0 * 16 + il] = acc0[r];
        lds_C[wave][q * 4 + r][1 * 16 + il] = acc1[r];
        lds_C[wave][q * 4 + r][2 * 16 + il] = acc2[r];
        lds_C[wave][q * 4 + r][3 * 16 + il] = acc3[r];
    }
    __syncthreads();

    // epilogue: cross-wave reduce, normalize, ELU, final store
#pragma unroll
    for (int e = 0; e < 2; ++e) {
        const int idx = e * 512 + tid;          // over 16*64 outputs
        const int ii = idx >> 6;
        const int ff = idx & 63;
        float s = 0.f;
#pragma unroll
        for (int w = 0; w < 8; ++w) s += lds_C[w][ii][ff];
        float t = lds_tot[0][ii] + lds_tot[1][ii] + lds_tot[2][ii] +
                  lds_tot[3][ii] + lds_tot[4][ii] + lds_tot[5][ii] +
                  lds_tot[6][ii] + lds_tot[7][ii];
        const float p = s / t;
        out[(size_t)(i0 + ii) * FOUT + ff] = (p > 0.f) ? p : (__expf(p) - 1.f);
    }
}

extern "C" void kernel_launch(void* const* d_in, const int* in_sizes, int n_in,
                              void* d_out, int out_size, void* d_ws, size_t ws_size,
                              hipStream_t stream) {
    const float* x   = (const float*)d_in[0];
    const int*   adj = (const int*)d_in[1];
    const float* W   = (const float*)d_in[2];
    const float* a   = (const float*)d_in[3];
    float* out = (float*)d_out;

    char* ws = (char*)d_ws;
    unsigned short* WhT = (unsigned short*)ws;                 // 1 MB @ 0
    float* Wh1   = (float*)(ws + (size_t)1048576);             // 32 KB
    float* Wh2   = (float*)(ws + (size_t)1048576 + 32768);     // 32 KB

    gat_prep<<<dim3(NN / 4), dim3(256), 0, stream>>>(x, W, a, WhT, Wh1, Wh2);
    gat_attn<<<dim3(NN / 16), dim3(512), 0, stream>>>(adj, WhT, Wh1, Wh2, out);
}

// Round 9
// 425.237 us; speedup vs baseline: 1.0233x; 1.0233x over previous
//
#include <hip/hip_runtime.h>
#include <hip/hip_bf16.h>
#include <cstdint>
#include <cstddef>

#define NN 8192
#define FIN 128
#define FOUT 64

typedef __attribute__((ext_vector_type(8))) short short8;
typedef __attribute__((ext_vector_type(4))) float f32x4;

__device__ __forceinline__ unsigned short f32_to_bf16_bits(float f) {
    union { float f; uint32_t u; } c; c.f = f;
    uint32_t u = c.u;
    u += 0x7fffu + ((u >> 16) & 1u);   // RNE
    return (unsigned short)(u >> 16);
}

// Kernel 1: Wh = x @ W^T (bf16, stored transposed [f][i]); Wh1 = Wh@a1; Wh2 = Wh@a2
__global__ __launch_bounds__(256) void gat_prep(
    const float* __restrict__ x, const float* __restrict__ W,
    const float* __restrict__ a, unsigned short* __restrict__ WhT,
    float* __restrict__ Wh1, float* __restrict__ Wh2)
{
    const int t    = threadIdx.x;
    const int f    = t & 63;        // lane = feature
    const int iloc = t >> 6;        // wave = local row
    const int i    = blockIdx.x * 4 + iloc;

    const float4* x4 = (const float4*)(x + (size_t)i * FIN);  // wave-uniform
    const float4* w4 = (const float4*)(W + (size_t)f * FIN);

    float acc = 0.f;
#pragma unroll
    for (int k = 0; k < FIN / 4; ++k) {
        float4 xv = x4[k];
        float4 wv = w4[k];
        acc += xv.x * wv.x + xv.y * wv.y + xv.z * wv.z + xv.w * wv.w;
    }

    WhT[(size_t)f * NN + i] = f32_to_bf16_bits(acc);

    float r1 = acc * a[f];
    float r2 = acc * a[64 + f];
#pragma unroll
    for (int m = 1; m < 64; m <<= 1) {
        r1 += __shfl_xor(r1, m, 64);
        r2 += __shfl_xor(r2, m, 64);
    }
    if (f == 0) { Wh1[i] = r1; Wh2[i] = r2; }
}

// Kernel 2 (fused, 32-row blocks): 256 blocks x 1024 threads (16 waves),
// exactly 1 block/CU (32/XCD). Each block owns a 32-ROW panel and the full
// j range; wave w covers j-strip [w*32 + tt*512, +32) for tt=0..15.
//
// Round-9 theory: R8's discriminator killed the latency and B-staging
// theories -> the loop is bound by L1 return bytes / load-issue slots.
// Serving 32 rows per block amortizes the SAME B fragments over 2x rows:
// B traffic per CU halves (2 MB -> 1 MB), loads per output element -37%.
// adj (mandatory 268 MB stream) unchanged, 1-deep prefetch (R8: deeper is
// useless). B + Wh2 JIT-early (R8: safe). Est ~120 VGPR < 128 cap.
__global__ __launch_bounds__(1024, 4) void gat_attn(
    const int* __restrict__ adj, const unsigned short* __restrict__ WhT,
    const float* __restrict__ Wh1, const float* __restrict__ Wh2,
    float* __restrict__ out)
{
    __shared__ float lds_C[16][32][66];   // pad 64->66: 2-way (free) aliasing
    __shared__ float lds_tot[16][32];

    const int tid  = threadIdx.x;
    const int wave = tid >> 6;       // 0..15
    const int lane = tid & 63;
    const int il   = lane & 15;      // A-fragment row within 16-row group
    const int q    = lane >> 4;      // quad -> k offset q*8
    const int i0   = blockIdx.x * 32;
    const int iA   = i0 + il;        // row-group A: rows 0..15
    const int iB   = i0 + 16 + il;   // row-group B: rows 16..31

    const float wh1A = Wh1[iA];
    const float wh1B = Wh1[iB];
    const int   jbase = wave * 32 + q * 8;
    const int* __restrict__ adjA = adj + (size_t)iA * NN;
    const int* __restrict__ adjB = adj + (size_t)iB * NN;

    const short8* bp0 = (const short8*)(WhT + (size_t)(0  + il) * NN);
    const short8* bp1 = (const short8*)(WhT + (size_t)(16 + il) * NN);
    const short8* bp2 = (const short8*)(WhT + (size_t)(32 + il) * NN);
    const short8* bp3 = (const short8*)(WhT + (size_t)(48 + il) * NN);

    f32x4 acc0 = {0.f, 0.f, 0.f, 0.f};
    f32x4 acc1 = {0.f, 0.f, 0.f, 0.f};
    f32x4 acc2 = {0.f, 0.f, 0.f, 0.f};
    f32x4 acc3 = {0.f, 0.f, 0.f, 0.f};
    f32x4 acc4 = {0.f, 0.f, 0.f, 0.f};
    f32x4 acc5 = {0.f, 0.f, 0.f, 0.f};
    f32x4 acc6 = {0.f, 0.f, 0.f, 0.f};
    f32x4 acc7 = {0.f, 0.f, 0.f, 0.f};
    float totA = 0.f, totB = 0.f;

    // ---- prologue: adj iter 0 (1-deep, both row-groups) ----
    int4 avA0 = *(const int4*)(adjA + jbase);
    int4 avA1 = *(const int4*)(adjA + jbase + 4);
    int4 avB0 = *(const int4*)(adjB + jbase);
    int4 avB1 = *(const int4*)(adjB + jbase + 4);

#pragma unroll 1
    for (int tt = 0; tt < 16; ++tt) {
        // ---- prefetch adj for iter tt+1 (stride 512; wraps on tail) ----
        const int jn = jbase + (((tt + 1) & 15) << 9);
        const int4 nA0 = *(const int4*)(adjA + jn);
        const int4 nA1 = *(const int4*)(adjA + jn + 4);
        const int4 nB0 = *(const int4*)(adjB + jn);
        const int4 nB1 = *(const int4*)(adjB + jn + 4);

        // ---- JIT-early Wh2 + B for THIS iteration (L1/L2-hot; consumed
        //      after the CALC/pack block below) ----
        const int j  = jbase + (tt << 9);
        const float4 w20 = *(const float4*)(Wh2 + j);
        const float4 w21 = *(const float4*)(Wh2 + j + 4);
        const int jb = j >> 3;
        const short8 b0 = bp0[jb];
        const short8 b1 = bp1[jb];
        const short8 b2 = bp2[jb];
        const short8 b3 = bp3[jb];

        float wv[8];
#define CALC(idx, adjv, wh1v, wh2v, totv)                              \
        {                                                              \
            float s = (wh1v) + (wh2v);                                 \
            float e = fmaxf(s, 0.2f * s);      /* leaky_relu 0.2 */    \
            float v = ((adjv) > 0) ? __expf(e) : 0.f;                  \
            totv += v;                                                 \
            wv[idx] = v;                                               \
        }
        // ---- row-group A ----
        CALC(0, avA0.x, wh1A, w20.x, totA) CALC(1, avA0.y, wh1A, w20.y, totA)
        CALC(2, avA0.z, wh1A, w20.z, totA) CALC(3, avA0.w, wh1A, w20.w, totA)
        CALC(4, avA1.x, wh1A, w21.x, totA) CALC(5, avA1.y, wh1A, w21.y, totA)
        CALC(6, avA1.z, wh1A, w21.z, totA) CALC(7, avA1.w, wh1A, w21.w, totA)
        union { short8 v; __hip_bfloat162 h[4]; } afA;
        afA.h[0] = __float22bfloat162_rn(float2{wv[0], wv[1]});
        afA.h[1] = __float22bfloat162_rn(float2{wv[2], wv[3]});
        afA.h[2] = __float22bfloat162_rn(float2{wv[4], wv[5]});
        afA.h[3] = __float22bfloat162_rn(float2{wv[6], wv[7]});

        // ---- row-group B ----
        CALC(0, avB0.x, wh1B, w20.x, totB) CALC(1, avB0.y, wh1B, w20.y, totB)
        CALC(2, avB0.z, wh1B, w20.z, totB) CALC(3, avB0.w, wh1B, w20.w, totB)
        CALC(4, avB1.x, wh1B, w21.x, totB) CALC(5, avB1.y, wh1B, w21.y, totB)
        CALC(6, avB1.z, wh1B, w21.z, totB) CALC(7, avB1.w, wh1B, w21.w, totB)
#undef CALC
        union { short8 v; __hip_bfloat162 h[4]; } afB;
        afB.h[0] = __float22bfloat162_rn(float2{wv[0], wv[1]});
        afB.h[1] = __float22bfloat162_rn(float2{wv[2], wv[3]});
        afB.h[2] = __float22bfloat162_rn(float2{wv[4], wv[5]});
        afB.h[3] = __float22bfloat162_rn(float2{wv[6], wv[7]});

        // ---- 8 MFMA: both row-groups share B fragments ----
        acc0 = __builtin_amdgcn_mfma_f32_16x16x32_bf16(afA.v, b0, acc0, 0, 0, 0);
        acc1 = __builtin_amdgcn_mfma_f32_16x16x32_bf16(afA.v, b1, acc1, 0, 0, 0);
        acc2 = __builtin_amdgcn_mfma_f32_16x16x32_bf16(afA.v, b2, acc2, 0, 0, 0);
        acc3 = __builtin_amdgcn_mfma_f32_16x16x32_bf16(afA.v, b3, acc3, 0, 0, 0);
        acc4 = __builtin_amdgcn_mfma_f32_16x16x32_bf16(afB.v, b0, acc4, 0, 0, 0);
        acc5 = __builtin_amdgcn_mfma_f32_16x16x32_bf16(afB.v, b1, acc5, 0, 0, 0);
        acc6 = __builtin_amdgcn_mfma_f32_16x16x32_bf16(afB.v, b2, acc6, 0, 0, 0);
        acc7 = __builtin_amdgcn_mfma_f32_16x16x32_bf16(afB.v, b3, acc7, 0, 0, 0);

        // ---- rotate adj (1-deep) ----
        avA0 = nA0; avA1 = nA1; avB0 = nB0; avB1 = nB1;
    }

    // row-total reduction: lanes {il, il+16, il+32, il+48} hold partials
    totA += __shfl_xor(totA, 16, 64);
    totA += __shfl_xor(totA, 32, 64);
    totB += __shfl_xor(totB, 16, 64);
    totB += __shfl_xor(totB, 32, 64);
    if (lane < 16) {
        lds_tot[wave][lane]      = totA;
        lds_tot[wave][16 + lane] = totB;
    }

    // C/D layout: col = lane&15 (f within tile), row = q*4 + reg (i)
#pragma unroll
    for (int r = 0; r < 4; ++r) {
        lds_C[wave][q * 4 + r][0 * 16 + il] = acc0[r];
        lds_C[wave][q * 4 + r][1 * 16 + il] = acc1[r];
        lds_C[wave][q * 4 + r][2 * 16 + il] = acc2[r];
        lds_C[wave][q * 4 + r][3 * 16 + il] = acc3[r];
        lds_C[wave][16 + q * 4 + r][0 * 16 + il] = acc4[r];
        lds_C[wave][16 + q * 4 + r][1 * 16 + il] = acc5[r];
        lds_C[wave][16 + q * 4 + r][2 * 16 + il] = acc6[r];
        lds_C[wave][16 + q * 4 + r][3 * 16 + il] = acc7[r];
    }
    __syncthreads();

    // epilogue: 16-wave reduce, normalize, ELU, final store (2048 outputs)
#pragma unroll
    for (int e = 0; e < 2; ++e) {
        const int idx = e * 1024 + tid;         // over 32*64 outputs
        const int ii = idx >> 6;
        const int ff = idx & 63;
        float s = 0.f;
        float t = 0.f;
#pragma unroll
        for (int w = 0; w < 16; ++w) {
            s += lds_C[w][ii][ff];
            t += lds_tot[w][ii];
        }
        const float p = s / t;
        out[(size_t)(i0 + ii) * FOUT + ff] = (p > 0.f) ? p : (__expf(p) - 1.f);
    }
}

extern "C" void kernel_launch(void* const* d_in, const int* in_sizes, int n_in,
                              void* d_out, int out_size, void* d_ws, size_t ws_size,
                              hipStream_t stream) {
    const float* x   = (const float*)d_in[0];
    const int*   adj = (const int*)d_in[1];
    const float* W   = (const float*)d_in[2];
    const float* a   = (const float*)d_in[3];
    float* out = (float*)d_out;

    char* ws = (char*)d_ws;
    unsigned short* WhT = (unsigned short*)ws;                 // 1 MB @ 0
    float* Wh1   = (float*)(ws + (size_t)1048576);             // 32 KB
    float* Wh2   = (float*)(ws + (size_t)1048576 + 32768);     // 32 KB

    gat_prep<<<dim3(NN / 4), dim3(256), 0, stream>>>(x, W, a, WhT, Wh1, Wh2);
    gat_attn<<<dim3(NN / 32), dim3(1024), 0, stream>>>(adj, WhT, Wh1, Wh2, out);
}